// Round 2
// baseline (986.858 us; speedup 1.0000x reference)
//
#include <hip/hip_runtime.h>

// ---------- degree histogram ----------
__global__ void hist_kernel(const int* __restrict__ dst, int* __restrict__ cnt, int E) {
    int i = blockIdx.x * 256 + threadIdx.x;
    if (i < E) atomicAdd(&cnt[dst[i]], 1);
}

// ---------- single-block scan: row_ptr, cursor, dis, self_norm ----------
__global__ __launch_bounds__(1024) void scan_kernel(const int* __restrict__ cnt,
        int* __restrict__ rowptr, int* __restrict__ cursor,
        float* __restrict__ dis, float* __restrict__ selfn, int n) {
    __shared__ int sums[1024];
    int tid = threadIdx.x;
    int CH = (n + 1023) >> 10;
    int s0 = tid * CH;
    int s1 = min(s0 + CH, n);
    int local = 0;
    for (int i = s0; i < s1; ++i) local += cnt[i];
    sums[tid] = local;
    __syncthreads();
    for (int off = 1; off < 1024; off <<= 1) {
        int v = sums[tid];
        int add = (tid >= off) ? sums[tid - off] : 0;
        __syncthreads();
        sums[tid] = v + add;
        __syncthreads();
    }
    int prefix = (tid == 0) ? 0 : sums[tid - 1];
    for (int i = s0; i < s1; ++i) {
        int c = cnt[i];
        rowptr[i] = prefix;
        cursor[i] = prefix;
        float d = (float)c + 1.0f;          // deg = in-degree + self-loop
        dis[i] = rsqrtf(d);
        selfn[i] = 1.0f / d;
        prefix += c;
    }
    if (tid == 0) rowptr[n] = sums[1023];
}

// ---------- CSR fill (per-dst edge lists with precomputed norm) ----------
__global__ void fill_kernel(const int* __restrict__ src, const int* __restrict__ dst,
        const float* __restrict__ dis, int* __restrict__ cursor,
        int* __restrict__ esrc, float* __restrict__ ew, int E) {
    int i = blockIdx.x * 256 + threadIdx.x;
    if (i < E) {
        int s = src[i], d = dst[i];
        int p = atomicAdd(&cursor[d], 1);
        esrc[p] = s;
        ew[p] = dis[s] * dis[d];
    }
}

// ---------- fp32 GEMM: C[n x MO] = A[n x 128] @ W[128 x MO] (+bias) ----------
// block: 256 thr, 128 rows x MO cols; thread: 8 rows (rowg+16j) x (MO/16) cols.
// W fully in LDS; A staged in 16-k chunks. In-place C==A is safe: block b only
// reads A rows [128b,128b+128) and writes the same rows strictly after all reads.
template<int MO>
__global__ __launch_bounds__(256) void gemm_kernel(const float* __restrict__ A,
        const float* __restrict__ W, const float* __restrict__ bias,
        float* __restrict__ C, int nrows) {
    constexpr int NC4 = MO / 64;                  // float4 clusters per thread (2 or 1)
    __shared__ float Wl[128 * MO];
    __shared__ float Al[128][20];                 // 16 k + pad 4
    const int tid  = threadIdx.x;
    const int colg = tid & 15;
    const int rowg = tid >> 4;                    // 0..15
    const int row_base = blockIdx.x * 128;

    for (int i = tid; i < 128 * MO / 4; i += 256)
        ((float4*)Wl)[i] = ((const float4*)W)[i];

    float4 acc[8][NC4];
#pragma unroll
    for (int i = 0; i < 8; ++i)
#pragma unroll
        for (int j = 0; j < NC4; ++j) acc[i][j] = make_float4(0.f, 0.f, 0.f, 0.f);

    for (int kc = 0; kc < 8; ++kc) {
        __syncthreads();
        for (int i = tid; i < 512; i += 256) {    // 128 rows x 4 float4
            int r = i >> 2, kq = i & 3;
            int gr = row_base + r; if (gr > nrows - 1) gr = nrows - 1;
            *(float4*)&Al[r][kq * 4] =
                *(const float4*)&A[(size_t)gr * 128 + kc * 16 + kq * 4];
        }
        __syncthreads();
#pragma unroll
        for (int k4 = 0; k4 < 4; ++k4) {
            float4 a[8];
#pragma unroll
            for (int i = 0; i < 8; ++i)
                a[i] = *(const float4*)&Al[rowg + 16 * i][k4 * 4];
#pragma unroll
            for (int kk = 0; kk < 4; ++kk) {
                const int k = kc * 16 + k4 * 4 + kk;
                float4 w[NC4];
#pragma unroll
                for (int j = 0; j < NC4; ++j)
                    w[j] = *(const float4*)&Wl[k * MO + colg * 4 + j * 64];
#pragma unroll
                for (int i = 0; i < 8; ++i) {
                    float av = ((const float*)&a[i])[kk];
#pragma unroll
                    for (int j = 0; j < NC4; ++j) {
                        acc[i][j].x = fmaf(av, w[j].x, acc[i][j].x);
                        acc[i][j].y = fmaf(av, w[j].y, acc[i][j].y);
                        acc[i][j].z = fmaf(av, w[j].z, acc[i][j].z);
                        acc[i][j].w = fmaf(av, w[j].w, acc[i][j].w);
                    }
                }
            }
        }
    }
    float4 bj[NC4];
#pragma unroll
    for (int j = 0; j < NC4; ++j) {
        if (bias) bj[j] = *(const float4*)&bias[colg * 4 + j * 64];
        else      bj[j] = make_float4(0.f, 0.f, 0.f, 0.f);
    }
#pragma unroll
    for (int i = 0; i < 8; ++i) {
        int gr = row_base + rowg + 16 * i;
        if (gr < nrows) {
#pragma unroll
            for (int j = 0; j < NC4; ++j) {
                float4 o;
                o.x = acc[i][j].x + bj[j].x;
                o.y = acc[i][j].y + bj[j].y;
                o.z = acc[i][j].z + bj[j].z;
                o.w = acc[i][j].w + bj[j].w;
                *(float4*)&C[(size_t)gr * MO + colg * 4 + j * 64] = o;
            }
        }
    }
}

// ---------- CSR gather aggregation: one wave per node, float2 per lane ----------
__global__ __launch_bounds__(256) void aggregate_kernel(const float* __restrict__ T,
        const int* __restrict__ rowptr, const int* __restrict__ esrc,
        const float* __restrict__ ew, const float* __restrict__ selfn,
        float* __restrict__ AGG, int n) {
    int wave = threadIdx.x >> 6;
    int lane = threadIdx.x & 63;
    int v = blockIdx.x * 4 + wave;
    if (v >= n) return;
    int c = lane * 2;
    float2 tv = *(const float2*)&T[(size_t)v * 128 + c];
    float sn = selfn[v];
    float ax = tv.x * sn, ay = tv.y * sn;
    int e = rowptr[v], e1 = rowptr[v + 1];
    for (; e < e1; ++e) {
        int u = esrc[e];
        float w = ew[e];
        float2 tu = *(const float2*)&T[(size_t)u * 128 + c];
        ax = fmaf(w, tu.x, ax);
        ay = fmaf(w, tu.y, ay);
    }
    *(float2*)&AGG[(size_t)v * 128 + c] = make_float2(ax, ay);
}

// ---------- BN stats (sum, sumsq per channel) ----------
__global__ __launch_bounds__(256) void bn_stats_kernel(const float* __restrict__ AGG,
        float* __restrict__ stats, int n) {
    __shared__ float s1[128], s2[128];
    int tid = threadIdx.x;
    int c = tid & 127;
    int half = tid >> 7;
    int v0 = blockIdx.x * 256;
    int vend = min(v0 + 256, n);
    float a1 = 0.f, a2 = 0.f;
    for (int v = v0 + half; v < vend; v += 2) {
        float x = AGG[(size_t)v * 128 + c];
        a1 += x; a2 = fmaf(x, x, a2);
    }
    if (half == 0) { s1[c] = a1; s2[c] = a2; }
    __syncthreads();
    if (half == 1) { s1[c] += a1; s2[c] += a2; }
    __syncthreads();
    if (half == 0) {
        atomicAdd(&stats[c], s1[c]);
        atomicAdd(&stats[128 + c], s2[c]);
    }
}

// ---------- BN finalize: A = inv_std*gamma, B = beta - mean*A ----------
__global__ void bn_finalize_kernel(const float* __restrict__ stats,
        const float* __restrict__ gamma, const float* __restrict__ beta,
        float* __restrict__ AB, float inv_n) {
    int c = threadIdx.x;
    float m = stats[c] * inv_n;
    float var = stats[128 + c] * inv_n - m * m;
    float inv = rsqrtf(var + 1e-5f);
    float Ax = inv * gamma[c];
    AB[c] = Ax;
    AB[128 + c] = beta[c] - m * Ax;
}

// ---------- BN apply + skip + relu + acc; writes H over the dead t-buffer ----------
__global__ __launch_bounds__(256) void bn_apply_kernel(const float* __restrict__ AGG,
        const float* __restrict__ AB, const float* __restrict__ XSKIP,
        float* __restrict__ H, float* __restrict__ ACC, int total4,
        int do_skip, int first) {
    int i = blockIdx.x * 256 + threadIdx.x;
    if (i >= total4) return;
    int c4 = i & 31;
    float4 x  = ((const float4*)AGG)[i];
    float4 Av = ((const float4*)AB)[c4];
    float4 Bv = ((const float4*)AB)[32 + c4];
    float4 t;
    t.x = fmaf(x.x, Av.x, Bv.x);
    t.y = fmaf(x.y, Av.y, Bv.y);
    t.z = fmaf(x.z, Av.z, Bv.z);
    t.w = fmaf(x.w, Av.w, Bv.w);
    if (do_skip) {
        float4 sk = ((const float4*)XSKIP)[i];
        t.x = fmaf(0.5f, sk.x, t.x);
        t.y = fmaf(0.5f, sk.y, t.y);
        t.z = fmaf(0.5f, sk.z, t.z);
        t.w = fmaf(0.5f, sk.w, t.w);
    }
    t.x = fmaxf(t.x, 0.f); t.y = fmaxf(t.y, 0.f);
    t.z = fmaxf(t.z, 0.f); t.w = fmaxf(t.w, 0.f);
    ((float4*)H)[i] = t;
    if (first) {
        ((float4*)ACC)[i] = t;
    } else {
        float4 a = ((const float4*)ACC)[i];
        a.x += t.x; a.y += t.y; a.z += t.z; a.w += t.w;
        ((float4*)ACC)[i] = a;
    }
}

extern "C" void kernel_launch(void* const* d_in, const int* in_sizes, int n_in,
                              void* d_out, int out_size, void* d_ws, size_t ws_size,
                              hipStream_t stream) {
    (void)n_in; (void)out_size; (void)ws_size;
    const float* x    = (const float*)d_in[0];
    const float* Win  = (const float*)d_in[1];
    const float* bin  = (const float*)d_in[2];
    const float* Wg   = (const float*)d_in[3];
    // d_in[4] = b_g: per-channel shift before BatchNorm -> cancelled by mean-subtract, unused.
    const float* gamma = (const float*)d_in[5];
    const float* beta  = (const float*)d_in[6];
    const float* Wout  = (const float*)d_in[7];
    const float* bout  = (const float*)d_in[8];
    const int*   eidx  = (const int*)d_in[9];
    float* out = (float*)d_out;

    const int N = in_sizes[0] / 128;   // 50000 nodes
    const int E = in_sizes[9] / 2;     // 600000 edges
    const int* esrc_in = eidx;
    const int* edst_in = eidx + E;

    char* p = (char*)d_ws;
    auto alloc = [&](size_t bytes) { char* r = p; p += (bytes + 255) & ~(size_t)255; return r; };
    const size_t NB = (size_t)N * 128 * sizeof(float);
    float* h0   = (float*)alloc(NB);   // x_skip
    float* hbuf = (float*)alloc(NB);   // t-buffer AND hidden state (in-place)
    float* agg  = (float*)alloc(NB);
    float* accb = (float*)alloc(NB);
    float* disb  = (float*)alloc((size_t)N * 4);
    float* selfn = (float*)alloc((size_t)N * 4);
    float* ewb   = (float*)alloc((size_t)E * 4);
    int*   cnt    = (int*)alloc((size_t)N * 4);
    int*   rowptr = (int*)alloc((size_t)(N + 1) * 4);
    int*   cursor = (int*)alloc((size_t)N * 4);
    int*   esrcb  = (int*)alloc((size_t)E * 4);
    float* stats  = (float*)alloc(256 * 4);
    float* AB     = (float*)alloc(256 * 4);

    auto cdiv = [](int a, int b) { return (a + b - 1) / b; };

    // graph preprocessing
    hipMemsetAsync(cnt, 0, (size_t)N * 4, stream);
    hist_kernel<<<cdiv(E, 256), 256, 0, stream>>>(edst_in, cnt, E);
    scan_kernel<<<1, 1024, 0, stream>>>(cnt, rowptr, cursor, disb, selfn, N);
    fill_kernel<<<cdiv(E, 256), 256, 0, stream>>>(esrc_in, edst_in, disb, cursor, esrcb, ewb, E);

    // h0 = x @ W_in + b_in   (x_skip)
    gemm_kernel<128><<<cdiv(N, 128), 256, 0, stream>>>(x, Win, bin, h0, N);

    const float* hcur = h0;
    for (int i = 0; i < 4; ++i) {
        // t = h @ W_g[i]   (in-place for i>=1: hbuf -> hbuf, block-local rows only)
        gemm_kernel<128><<<cdiv(N, 128), 256, 0, stream>>>(hcur, Wg + (size_t)i * 128 * 128,
                                                           nullptr, hbuf, N);
        aggregate_kernel<<<cdiv(N, 4), 256, 0, stream>>>(hbuf, rowptr, esrcb, ewb, selfn, agg, N);
        hipMemsetAsync(stats, 0, 256 * 4, stream);
        bn_stats_kernel<<<cdiv(N, 256), 256, 0, stream>>>(agg, stats, N);
        bn_finalize_kernel<<<1, 128, 0, stream>>>(stats, gamma + i * 128, beta + i * 128,
                                                  AB, 1.0f / (float)N);
        // H overwrites the dead t-buffer (hbuf); ACC accumulates
        bn_apply_kernel<<<cdiv(N * 32, 256), 256, 0, stream>>>(agg, AB, h0, hbuf, accb, N * 32,
                                                               (i & 1), (i == 0) ? 1 : 0);
        hcur = hbuf;
    }

    // out = acc @ W_out + b_out
    gemm_kernel<64><<<cdiv(N, 128), 256, 0, stream>>>(accb, Wout, bout, out, N);
}

// Round 3
// 849.930 us; speedup vs baseline: 1.1611x; 1.1611x over previous
//
#include <hip/hip_runtime.h>

// ---------- degree histogram ----------
__global__ void hist_kernel(const int* __restrict__ dst, int* __restrict__ cnt, int E) {
    int i = blockIdx.x * 256 + threadIdx.x;
    if (i < E) atomicAdd(&cnt[dst[i]], 1);
}

// ---------- 3-phase parallel exclusive scan over cnt[0..n) ----------
// Phase 1: per-block (256-wide) reduction -> bsum[block]
__global__ __launch_bounds__(256) void scan1_kernel(const int* __restrict__ cnt,
        int* __restrict__ bsum, int n) {
    __shared__ int s[256];
    int i = blockIdx.x * 256 + threadIdx.x;
    s[threadIdx.x] = (i < n) ? cnt[i] : 0;
    __syncthreads();
    for (int off = 128; off > 0; off >>= 1) {
        if (threadIdx.x < off) s[threadIdx.x] += s[threadIdx.x + off];
        __syncthreads();
    }
    if (threadIdx.x == 0) bsum[blockIdx.x] = s[0];
}

// Phase 2: single block exclusive scan of bsum[0..nb) (nb <= 256)
__global__ __launch_bounds__(256) void scan2_kernel(int* __restrict__ bsum, int nb) {
    __shared__ int s[256];
    int v = (threadIdx.x < nb) ? bsum[threadIdx.x] : 0;
    s[threadIdx.x] = v;
    __syncthreads();
    for (int off = 1; off < 256; off <<= 1) {
        int t = s[threadIdx.x];
        int a = (threadIdx.x >= off) ? s[threadIdx.x - off] : 0;
        __syncthreads();
        s[threadIdx.x] = t + a;
        __syncthreads();
    }
    if (threadIdx.x < nb) bsum[threadIdx.x] = s[threadIdx.x] - v;   // exclusive
}

// Phase 3: per-block scan + block offset -> rowptr/cursor/dis/selfn
__global__ __launch_bounds__(256) void scan3_kernel(const int* __restrict__ cnt,
        const int* __restrict__ boff, int* __restrict__ rowptr, int* __restrict__ cursor,
        float* __restrict__ dis, float* __restrict__ selfn, int n) {
    __shared__ int s[256];
    int i = blockIdx.x * 256 + threadIdx.x;
    int c = (i < n) ? cnt[i] : 0;
    s[threadIdx.x] = c;
    __syncthreads();
    for (int off = 1; off < 256; off <<= 1) {
        int t = s[threadIdx.x];
        int a = (threadIdx.x >= off) ? s[threadIdx.x - off] : 0;
        __syncthreads();
        s[threadIdx.x] = t + a;
        __syncthreads();
    }
    if (i < n) {
        int pre = boff[blockIdx.x] + s[threadIdx.x] - c;  // exclusive prefix
        rowptr[i] = pre;
        cursor[i] = pre;
        float d = (float)c + 1.0f;          // deg = in-degree + self-loop
        dis[i] = rsqrtf(d);
        selfn[i] = 1.0f / d;
        if (i == n - 1) rowptr[n] = pre + c;
    }
}

// ---------- CSR fill (per-dst edge lists with precomputed norm) ----------
__global__ void fill_kernel(const int* __restrict__ src, const int* __restrict__ dst,
        const float* __restrict__ dis, int* __restrict__ cursor,
        int* __restrict__ esrc, float* __restrict__ ew, int E) {
    int i = blockIdx.x * 256 + threadIdx.x;
    if (i < E) {
        int s = src[i], d = dst[i];
        int p = atomicAdd(&cursor[d], 1);
        esrc[p] = s;
        ew[p] = dis[s] * dis[d];
    }
}

// ---------- fp32 GEMM: C[n x MO] = A[n x 128] @ W[128 x MO] (+bias) ----------
// block: 256 thr, 128 rows x MO cols; thread: 8 rows (rowg+16j) x (MO/16) cols.
// W fully in LDS; A staged in 16-k chunks. In-place C==A is safe: block b only
// reads A rows [128b,128b+128) and writes the same rows strictly after all reads.
template<int MO>
__global__ __launch_bounds__(256) void gemm_kernel(const float* __restrict__ A,
        const float* __restrict__ W, const float* __restrict__ bias,
        float* __restrict__ C, int nrows) {
    constexpr int NC4 = MO / 64;                  // float4 clusters per thread (2 or 1)
    __shared__ float Wl[128 * MO];
    __shared__ float Al[128][20];                 // 16 k + pad 4
    const int tid  = threadIdx.x;
    const int colg = tid & 15;
    const int rowg = tid >> 4;                    // 0..15
    const int row_base = blockIdx.x * 128;

    for (int i = tid; i < 128 * MO / 4; i += 256)
        ((float4*)Wl)[i] = ((const float4*)W)[i];

    float4 acc[8][NC4];
#pragma unroll
    for (int i = 0; i < 8; ++i)
#pragma unroll
        for (int j = 0; j < NC4; ++j) acc[i][j] = make_float4(0.f, 0.f, 0.f, 0.f);

    for (int kc = 0; kc < 8; ++kc) {
        __syncthreads();
        for (int i = tid; i < 512; i += 256) {    // 128 rows x 4 float4
            int r = i >> 2, kq = i & 3;
            int gr = row_base + r; if (gr > nrows - 1) gr = nrows - 1;
            *(float4*)&Al[r][kq * 4] =
                *(const float4*)&A[(size_t)gr * 128 + kc * 16 + kq * 4];
        }
        __syncthreads();
#pragma unroll
        for (int k4 = 0; k4 < 4; ++k4) {
            float4 a[8];
#pragma unroll
            for (int i = 0; i < 8; ++i)
                a[i] = *(const float4*)&Al[rowg + 16 * i][k4 * 4];
#pragma unroll
            for (int kk = 0; kk < 4; ++kk) {
                const int k = kc * 16 + k4 * 4 + kk;
                float4 w[NC4];
#pragma unroll
                for (int j = 0; j < NC4; ++j)
                    w[j] = *(const float4*)&Wl[k * MO + colg * 4 + j * 64];
#pragma unroll
                for (int i = 0; i < 8; ++i) {
                    float av = ((const float*)&a[i])[kk];
#pragma unroll
                    for (int j = 0; j < NC4; ++j) {
                        acc[i][j].x = fmaf(av, w[j].x, acc[i][j].x);
                        acc[i][j].y = fmaf(av, w[j].y, acc[i][j].y);
                        acc[i][j].z = fmaf(av, w[j].z, acc[i][j].z);
                        acc[i][j].w = fmaf(av, w[j].w, acc[i][j].w);
                    }
                }
            }
        }
    }
    float4 bj[NC4];
#pragma unroll
    for (int j = 0; j < NC4; ++j) {
        if (bias) bj[j] = *(const float4*)&bias[colg * 4 + j * 64];
        else      bj[j] = make_float4(0.f, 0.f, 0.f, 0.f);
    }
#pragma unroll
    for (int i = 0; i < 8; ++i) {
        int gr = row_base + rowg + 16 * i;
        if (gr < nrows) {
#pragma unroll
            for (int j = 0; j < NC4; ++j) {
                float4 o;
                o.x = acc[i][j].x + bj[j].x;
                o.y = acc[i][j].y + bj[j].y;
                o.z = acc[i][j].z + bj[j].z;
                o.w = acc[i][j].w + bj[j].w;
                *(float4*)&C[(size_t)gr * MO + colg * 4 + j * 64] = o;
            }
        }
    }
}

// ---------- CSR gather aggregation: one wave per node, float2 per lane ----------
__global__ __launch_bounds__(256) void aggregate_kernel(const float* __restrict__ T,
        const int* __restrict__ rowptr, const int* __restrict__ esrc,
        const float* __restrict__ ew, const float* __restrict__ selfn,
        float* __restrict__ AGG, int n) {
    int wave = threadIdx.x >> 6;
    int lane = threadIdx.x & 63;
    int v = blockIdx.x * 4 + wave;
    if (v >= n) return;
    int c = lane * 2;
    float2 tv = *(const float2*)&T[(size_t)v * 128 + c];
    float sn = selfn[v];
    float ax = tv.x * sn, ay = tv.y * sn;
    int e = rowptr[v], e1 = rowptr[v + 1];
    for (; e < e1; ++e) {
        int u = esrc[e];
        float w = ew[e];
        float2 tu = *(const float2*)&T[(size_t)u * 128 + c];
        ax = fmaf(w, tu.x, ax);
        ay = fmaf(w, tu.y, ay);
    }
    *(float2*)&AGG[(size_t)v * 128 + c] = make_float2(ax, ay);
}

// ---------- BN stats (sum, sumsq per channel) ----------
__global__ __launch_bounds__(256) void bn_stats_kernel(const float* __restrict__ AGG,
        float* __restrict__ stats, int n) {
    __shared__ float s1[128], s2[128];
    int tid = threadIdx.x;
    int c = tid & 127;
    int half = tid >> 7;
    int v0 = blockIdx.x * 256;
    int vend = min(v0 + 256, n);
    float a1 = 0.f, a2 = 0.f;
    for (int v = v0 + half; v < vend; v += 2) {
        float x = AGG[(size_t)v * 128 + c];
        a1 += x; a2 = fmaf(x, x, a2);
    }
    if (half == 0) { s1[c] = a1; s2[c] = a2; }
    __syncthreads();
    if (half == 1) { s1[c] += a1; s2[c] += a2; }
    __syncthreads();
    if (half == 0) {
        atomicAdd(&stats[c], s1[c]);
        atomicAdd(&stats[128 + c], s2[c]);
    }
}

// ---------- BN finalize: A = inv_std*gamma, B = beta - mean*A ----------
__global__ void bn_finalize_kernel(const float* __restrict__ stats,
        const float* __restrict__ gamma, const float* __restrict__ beta,
        float* __restrict__ AB, float inv_n) {
    int c = threadIdx.x;
    float m = stats[c] * inv_n;
    float var = stats[128 + c] * inv_n - m * m;
    float inv = rsqrtf(var + 1e-5f);
    float Ax = inv * gamma[c];
    AB[c] = Ax;
    AB[128 + c] = beta[c] - m * Ax;
}

// ---------- BN apply + skip + relu + acc; writes H over the dead t-buffer ----------
__global__ __launch_bounds__(256) void bn_apply_kernel(const float* __restrict__ AGG,
        const float* __restrict__ AB, const float* __restrict__ XSKIP,
        float* __restrict__ H, float* __restrict__ ACC, int total4,
        int do_skip, int first) {
    int i = blockIdx.x * 256 + threadIdx.x;
    if (i >= total4) return;
    int c4 = i & 31;
    float4 x  = ((const float4*)AGG)[i];
    float4 Av = ((const float4*)AB)[c4];
    float4 Bv = ((const float4*)AB)[32 + c4];
    float4 t;
    t.x = fmaf(x.x, Av.x, Bv.x);
    t.y = fmaf(x.y, Av.y, Bv.y);
    t.z = fmaf(x.z, Av.z, Bv.z);
    t.w = fmaf(x.w, Av.w, Bv.w);
    if (do_skip) {
        float4 sk = ((const float4*)XSKIP)[i];
        t.x = fmaf(0.5f, sk.x, t.x);
        t.y = fmaf(0.5f, sk.y, t.y);
        t.z = fmaf(0.5f, sk.z, t.z);
        t.w = fmaf(0.5f, sk.w, t.w);
    }
    t.x = fmaxf(t.x, 0.f); t.y = fmaxf(t.y, 0.f);
    t.z = fmaxf(t.z, 0.f); t.w = fmaxf(t.w, 0.f);
    ((float4*)H)[i] = t;
    if (first) {
        ((float4*)ACC)[i] = t;
    } else {
        float4 a = ((const float4*)ACC)[i];
        a.x += t.x; a.y += t.y; a.z += t.z; a.w += t.w;
        ((float4*)ACC)[i] = a;
    }
}

extern "C" void kernel_launch(void* const* d_in, const int* in_sizes, int n_in,
                              void* d_out, int out_size, void* d_ws, size_t ws_size,
                              hipStream_t stream) {
    (void)n_in; (void)out_size; (void)ws_size;
    const float* x    = (const float*)d_in[0];
    const float* Win  = (const float*)d_in[1];
    const float* bin  = (const float*)d_in[2];
    const float* Wg   = (const float*)d_in[3];
    // d_in[4] = b_g: per-channel shift before BatchNorm -> cancelled by mean-subtract, unused.
    const float* gamma = (const float*)d_in[5];
    const float* beta  = (const float*)d_in[6];
    const float* Wout  = (const float*)d_in[7];
    const float* bout  = (const float*)d_in[8];
    const int*   eidx  = (const int*)d_in[9];
    float* out = (float*)d_out;

    const int N = in_sizes[0] / 128;   // 50000 nodes
    const int E = in_sizes[9] / 2;     // 600000 edges
    const int* esrc_in = eidx;
    const int* edst_in = eidx + E;

    char* p = (char*)d_ws;
    auto alloc = [&](size_t bytes) { char* r = p; p += (bytes + 255) & ~(size_t)255; return r; };
    const size_t NB = (size_t)N * 128 * sizeof(float);
    float* h0   = (float*)alloc(NB);   // x_skip
    float* hbuf = (float*)alloc(NB);   // t-buffer AND hidden state (in-place)
    float* agg  = (float*)alloc(NB);
    float* accb = (float*)alloc(NB);
    float* disb  = (float*)alloc((size_t)N * 4);
    float* selfn = (float*)alloc((size_t)N * 4);
    float* ewb   = (float*)alloc((size_t)E * 4);
    int*   cnt    = (int*)alloc((size_t)N * 4);
    int*   rowptr = (int*)alloc((size_t)(N + 1) * 4);
    int*   cursor = (int*)alloc((size_t)N * 4);
    int*   esrcb  = (int*)alloc((size_t)E * 4);
    int*   bsum   = (int*)alloc(256 * 4);
    float* stats  = (float*)alloc(256 * 4);
    float* AB     = (float*)alloc(256 * 4);

    auto cdiv = [](int a, int b) { return (a + b - 1) / b; };
    const int NBLK = cdiv(N, 256);     // 196 scan blocks

    // graph preprocessing
    hipMemsetAsync(cnt, 0, (size_t)N * 4, stream);
    hist_kernel<<<cdiv(E, 256), 256, 0, stream>>>(edst_in, cnt, E);
    scan1_kernel<<<NBLK, 256, 0, stream>>>(cnt, bsum, N);
    scan2_kernel<<<1, 256, 0, stream>>>(bsum, NBLK);
    scan3_kernel<<<NBLK, 256, 0, stream>>>(cnt, bsum, rowptr, cursor, disb, selfn, N);
    fill_kernel<<<cdiv(E, 256), 256, 0, stream>>>(esrc_in, edst_in, disb, cursor, esrcb, ewb, E);

    // h0 = x @ W_in + b_in   (x_skip)
    gemm_kernel<128><<<cdiv(N, 128), 256, 0, stream>>>(x, Win, bin, h0, N);

    const float* hcur = h0;
    for (int i = 0; i < 4; ++i) {
        // t = h @ W_g[i]   (in-place for i>=1: hbuf -> hbuf, block-local rows only)
        gemm_kernel<128><<<cdiv(N, 128), 256, 0, stream>>>(hcur, Wg + (size_t)i * 128 * 128,
                                                           nullptr, hbuf, N);
        aggregate_kernel<<<cdiv(N, 4), 256, 0, stream>>>(hbuf, rowptr, esrcb, ewb, selfn, agg, N);
        hipMemsetAsync(stats, 0, 256 * 4, stream);
        bn_stats_kernel<<<cdiv(N, 256), 256, 0, stream>>>(agg, stats, N);
        bn_finalize_kernel<<<1, 128, 0, stream>>>(stats, gamma + i * 128, beta + i * 128,
                                                  AB, 1.0f / (float)N);
        // H overwrites the dead t-buffer (hbuf); ACC accumulates
        bn_apply_kernel<<<cdiv(N * 32, 256), 256, 0, stream>>>(agg, AB, h0, hbuf, accb, N * 32,
                                                               (i & 1), (i == 0) ? 1 : 0);
        hcur = hbuf;
    }

    // out = acc @ W_out + b_out
    gemm_kernel<64><<<cdiv(N, 128), 256, 0, stream>>>(accb, Wout, bout, out, N);
}

// Round 4
// 818.803 us; speedup vs baseline: 1.2052x; 1.0380x over previous
//
#include <hip/hip_runtime.h>

// ---------- bf16 helpers ----------
static __device__ __forceinline__ float bf2f(unsigned short u) {
    union { unsigned u; float f; } v; v.u = ((unsigned)u) << 16; return v.f;
}
static __device__ __forceinline__ unsigned short f2bf(float f) {
    union { float f; unsigned u; } v; v.f = f;
    unsigned r = v.u + 0x7FFFu + ((v.u >> 16) & 1u);   // round-to-nearest-even
    return (unsigned short)(r >> 16);
}

// ---------- degree histogram ----------
__global__ void hist_kernel(const int* __restrict__ dst, int* __restrict__ cnt, int E) {
    int i = blockIdx.x * 256 + threadIdx.x;
    if (i < E) atomicAdd(&cnt[dst[i]], 1);
}

// ---------- 3-phase parallel exclusive scan over cnt[0..n) ----------
__global__ __launch_bounds__(256) void scan1_kernel(const int* __restrict__ cnt,
        int* __restrict__ bsum, int n) {
    __shared__ int s[256];
    int i = blockIdx.x * 256 + threadIdx.x;
    s[threadIdx.x] = (i < n) ? cnt[i] : 0;
    __syncthreads();
    for (int off = 128; off > 0; off >>= 1) {
        if (threadIdx.x < off) s[threadIdx.x] += s[threadIdx.x + off];
        __syncthreads();
    }
    if (threadIdx.x == 0) bsum[blockIdx.x] = s[0];
}

__global__ __launch_bounds__(256) void scan2_kernel(int* __restrict__ bsum, int nb) {
    __shared__ int s[256];
    int v = (threadIdx.x < nb) ? bsum[threadIdx.x] : 0;
    s[threadIdx.x] = v;
    __syncthreads();
    for (int off = 1; off < 256; off <<= 1) {
        int t = s[threadIdx.x];
        int a = (threadIdx.x >= off) ? s[threadIdx.x - off] : 0;
        __syncthreads();
        s[threadIdx.x] = t + a;
        __syncthreads();
    }
    if (threadIdx.x < nb) bsum[threadIdx.x] = s[threadIdx.x] - v;   // exclusive
}

__global__ __launch_bounds__(256) void scan3_kernel(const int* __restrict__ cnt,
        const int* __restrict__ boff, int* __restrict__ rowptr, int* __restrict__ cursor,
        float* __restrict__ dis, float* __restrict__ selfn, int n) {
    __shared__ int s[256];
    int i = blockIdx.x * 256 + threadIdx.x;
    int c = (i < n) ? cnt[i] : 0;
    s[threadIdx.x] = c;
    __syncthreads();
    for (int off = 1; off < 256; off <<= 1) {
        int t = s[threadIdx.x];
        int a = (threadIdx.x >= off) ? s[threadIdx.x - off] : 0;
        __syncthreads();
        s[threadIdx.x] = t + a;
        __syncthreads();
    }
    if (i < n) {
        int pre = boff[blockIdx.x] + s[threadIdx.x] - c;  // exclusive prefix
        rowptr[i] = pre;
        cursor[i] = pre;
        float d = (float)c + 1.0f;          // deg = in-degree + self-loop
        dis[i] = rsqrtf(d);
        selfn[i] = 1.0f / d;
        if (i == n - 1) rowptr[n] = pre + c;
    }
}

// ---------- CSR fill ----------
__global__ void fill_kernel(const int* __restrict__ src, const int* __restrict__ dst,
        const float* __restrict__ dis, int* __restrict__ cursor,
        int* __restrict__ esrc, float* __restrict__ ew, int E) {
    int i = blockIdx.x * 256 + threadIdx.x;
    if (i < E) {
        int s = src[i], d = dst[i];
        int p = atomicAdd(&cursor[d], 1);
        esrc[p] = s;
        ew[p] = dis[s] * dis[d];
    }
}

// ---------- fp32 GEMM: C[n x MO] = A[n x 128] @ W[128 x MO] (+bias) ----------
// OB16: round output to packed bf16 (for the t-buffer the gather reads).
template<int MO, bool OB16>
__global__ __launch_bounds__(256) void gemm_kernel(const float* __restrict__ A,
        const float* __restrict__ W, const float* __restrict__ bias,
        void* __restrict__ C, int nrows) {
    constexpr int NC4 = MO / 64;                  // float4 clusters per thread (2 or 1)
    __shared__ float Wl[128 * MO];
    __shared__ float Al[128][20];                 // 16 k + pad 4
    const int tid  = threadIdx.x;
    const int colg = tid & 15;
    const int rowg = tid >> 4;                    // 0..15
    const int row_base = blockIdx.x * 128;

    for (int i = tid; i < 128 * MO / 4; i += 256)
        ((float4*)Wl)[i] = ((const float4*)W)[i];

    float4 acc[8][NC4];
#pragma unroll
    for (int i = 0; i < 8; ++i)
#pragma unroll
        for (int j = 0; j < NC4; ++j) acc[i][j] = make_float4(0.f, 0.f, 0.f, 0.f);

    for (int kc = 0; kc < 8; ++kc) {
        __syncthreads();
        for (int i = tid; i < 512; i += 256) {    // 128 rows x 4 float4
            int r = i >> 2, kq = i & 3;
            int gr = row_base + r; if (gr > nrows - 1) gr = nrows - 1;
            *(float4*)&Al[r][kq * 4] =
                *(const float4*)&A[(size_t)gr * 128 + kc * 16 + kq * 4];
        }
        __syncthreads();
#pragma unroll
        for (int k4 = 0; k4 < 4; ++k4) {
            float4 a[8];
#pragma unroll
            for (int i = 0; i < 8; ++i)
                a[i] = *(const float4*)&Al[rowg + 16 * i][k4 * 4];
#pragma unroll
            for (int kk = 0; kk < 4; ++kk) {
                const int k = kc * 16 + k4 * 4 + kk;
                float4 w[NC4];
#pragma unroll
                for (int j = 0; j < NC4; ++j)
                    w[j] = *(const float4*)&Wl[k * MO + colg * 4 + j * 64];
#pragma unroll
                for (int i = 0; i < 8; ++i) {
                    float av = ((const float*)&a[i])[kk];
#pragma unroll
                    for (int j = 0; j < NC4; ++j) {
                        acc[i][j].x = fmaf(av, w[j].x, acc[i][j].x);
                        acc[i][j].y = fmaf(av, w[j].y, acc[i][j].y);
                        acc[i][j].z = fmaf(av, w[j].z, acc[i][j].z);
                        acc[i][j].w = fmaf(av, w[j].w, acc[i][j].w);
                    }
                }
            }
        }
    }
    float4 bj[NC4];
#pragma unroll
    for (int j = 0; j < NC4; ++j) {
        if (bias) bj[j] = *(const float4*)&bias[colg * 4 + j * 64];
        else      bj[j] = make_float4(0.f, 0.f, 0.f, 0.f);
    }
#pragma unroll
    for (int i = 0; i < 8; ++i) {
        int gr = row_base + rowg + 16 * i;
        if (gr < nrows) {
#pragma unroll
            for (int j = 0; j < NC4; ++j) {
                float4 o;
                o.x = acc[i][j].x + bj[j].x;
                o.y = acc[i][j].y + bj[j].y;
                o.z = acc[i][j].z + bj[j].z;
                o.w = acc[i][j].w + bj[j].w;
                int cc = colg * 4 + j * 64;
                if (OB16) {
                    ushort4 u;
                    u.x = f2bf(o.x); u.y = f2bf(o.y); u.z = f2bf(o.z); u.w = f2bf(o.w);
                    *(ushort4*)((unsigned short*)C + (size_t)gr * MO + cc) = u;
                } else {
                    *(float4*)((float*)C + (size_t)gr * MO + cc) = o;
                }
            }
        }
    }
}

// ---------- CSR gather aggregation (bf16 T): one wave per node, 2 ch/lane ----------
__global__ __launch_bounds__(256) void aggregate_kernel(const unsigned short* __restrict__ T,
        const int* __restrict__ rowptr, const int* __restrict__ esrc,
        const float* __restrict__ ew, const float* __restrict__ selfn,
        float* __restrict__ AGG, int n) {
    int wave = threadIdx.x >> 6;
    int lane = threadIdx.x & 63;
    int v = blockIdx.x * 4 + wave;
    if (v >= n) return;
    int c = lane * 2;
    ushort2 tv = *(const ushort2*)&T[(size_t)v * 128 + c];
    float sn = selfn[v];
    float ax = bf2f(tv.x) * sn, ay = bf2f(tv.y) * sn;
    int e = rowptr[v], e1 = rowptr[v + 1];
    // 2-way unrolled edge loop: two outstanding row-gathers per lane
    for (; e + 2 <= e1; e += 2) {
        int u0 = esrc[e], u1 = esrc[e + 1];
        float w0 = ew[e], w1 = ew[e + 1];
        ushort2 t0 = *(const ushort2*)&T[(size_t)u0 * 128 + c];
        ushort2 t1 = *(const ushort2*)&T[(size_t)u1 * 128 + c];
        ax = fmaf(w0, bf2f(t0.x), ax);
        ay = fmaf(w0, bf2f(t0.y), ay);
        ax = fmaf(w1, bf2f(t1.x), ax);
        ay = fmaf(w1, bf2f(t1.y), ay);
    }
    if (e < e1) {
        int u = esrc[e];
        float w = ew[e];
        ushort2 tu = *(const ushort2*)&T[(size_t)u * 128 + c];
        ax = fmaf(w, bf2f(tu.x), ax);
        ay = fmaf(w, bf2f(tu.y), ay);
    }
    *(float2*)&AGG[(size_t)v * 128 + c] = make_float2(ax, ay);
}

// ---------- BN stats (sum, sumsq per channel) ----------
__global__ __launch_bounds__(256) void bn_stats_kernel(const float* __restrict__ AGG,
        float* __restrict__ stats, int n) {
    __shared__ float s1[128], s2[128];
    int tid = threadIdx.x;
    int c = tid & 127;
    int half = tid >> 7;
    int v0 = blockIdx.x * 256;
    int vend = min(v0 + 256, n);
    float a1 = 0.f, a2 = 0.f;
    for (int v = v0 + half; v < vend; v += 2) {
        float x = AGG[(size_t)v * 128 + c];
        a1 += x; a2 = fmaf(x, x, a2);
    }
    if (half == 0) { s1[c] = a1; s2[c] = a2; }
    __syncthreads();
    if (half == 1) { s1[c] += a1; s2[c] += a2; }
    __syncthreads();
    if (half == 0) {
        atomicAdd(&stats[c], s1[c]);
        atomicAdd(&stats[128 + c], s2[c]);
    }
}

// ---------- BN finalize: A = inv_std*gamma, B = beta - mean*A ----------
__global__ void bn_finalize_kernel(const float* __restrict__ stats,
        const float* __restrict__ gamma, const float* __restrict__ beta,
        float* __restrict__ AB, float inv_n) {
    int c = threadIdx.x;
    float m = stats[c] * inv_n;
    float var = stats[128 + c] * inv_n - m * m;
    float inv = rsqrtf(var + 1e-5f);
    float Ax = inv * gamma[c];
    AB[c] = Ax;
    AB[128 + c] = beta[c] - m * Ax;
}

// ---------- BN apply + skip + relu + acc ----------
__global__ __launch_bounds__(256) void bn_apply_kernel(const float* __restrict__ AGG,
        const float* __restrict__ AB, const float* __restrict__ XSKIP,
        float* __restrict__ H, float* __restrict__ ACC, int total4,
        int do_skip, int first) {
    int i = blockIdx.x * 256 + threadIdx.x;
    if (i >= total4) return;
    int c4 = i & 31;
    float4 x  = ((const float4*)AGG)[i];
    float4 Av = ((const float4*)AB)[c4];
    float4 Bv = ((const float4*)AB)[32 + c4];
    float4 t;
    t.x = fmaf(x.x, Av.x, Bv.x);
    t.y = fmaf(x.y, Av.y, Bv.y);
    t.z = fmaf(x.z, Av.z, Bv.z);
    t.w = fmaf(x.w, Av.w, Bv.w);
    if (do_skip) {
        float4 sk = ((const float4*)XSKIP)[i];
        t.x = fmaf(0.5f, sk.x, t.x);
        t.y = fmaf(0.5f, sk.y, t.y);
        t.z = fmaf(0.5f, sk.z, t.z);
        t.w = fmaf(0.5f, sk.w, t.w);
    }
    t.x = fmaxf(t.x, 0.f); t.y = fmaxf(t.y, 0.f);
    t.z = fmaxf(t.z, 0.f); t.w = fmaxf(t.w, 0.f);
    ((float4*)H)[i] = t;
    if (first) {
        ((float4*)ACC)[i] = t;
    } else {
        float4 a = ((const float4*)ACC)[i];
        a.x += t.x; a.y += t.y; a.z += t.z; a.w += t.w;
        ((float4*)ACC)[i] = a;
    }
}

extern "C" void kernel_launch(void* const* d_in, const int* in_sizes, int n_in,
                              void* d_out, int out_size, void* d_ws, size_t ws_size,
                              hipStream_t stream) {
    (void)n_in; (void)out_size; (void)ws_size;
    const float* x    = (const float*)d_in[0];
    const float* Win  = (const float*)d_in[1];
    const float* bin  = (const float*)d_in[2];
    const float* Wg   = (const float*)d_in[3];
    // d_in[4] = b_g: cancelled by BN mean-subtract, unused.
    const float* gamma = (const float*)d_in[5];
    const float* beta  = (const float*)d_in[6];
    const float* Wout  = (const float*)d_in[7];
    const float* bout  = (const float*)d_in[8];
    const int*   eidx  = (const int*)d_in[9];
    float* out = (float*)d_out;

    const int N = in_sizes[0] / 128;   // 50000 nodes
    const int E = in_sizes[9] / 2;     // 600000 edges
    const int* esrc_in = eidx;
    const int* edst_in = eidx + E;

    char* p = (char*)d_ws;
    auto alloc = [&](size_t bytes) { char* r = p; p += (bytes + 255) & ~(size_t)255; return r; };
    const size_t NB = (size_t)N * 128 * sizeof(float);
    float* h0   = (float*)alloc(NB);                 // x_skip
    float* hbuf = (float*)alloc(NB);                 // hidden state H (fp32)
    float* agg  = (float*)alloc(NB);
    float* accb = (float*)alloc(NB);
    unsigned short* tb16 = (unsigned short*)alloc((size_t)N * 128 * 2);  // t in bf16
    float* disb  = (float*)alloc((size_t)N * 4);
    float* selfn = (float*)alloc((size_t)N * 4);
    float* ewb   = (float*)alloc((size_t)E * 4);
    int*   cnt    = (int*)alloc((size_t)N * 4);
    int*   rowptr = (int*)alloc((size_t)(N + 1) * 4);
    int*   cursor = (int*)alloc((size_t)N * 4);
    int*   esrcb  = (int*)alloc((size_t)E * 4);
    int*   bsum   = (int*)alloc(256 * 4);
    float* stats  = (float*)alloc(256 * 4);
    float* AB     = (float*)alloc(256 * 4);

    auto cdiv = [](int a, int b) { return (a + b - 1) / b; };
    const int NBLK = cdiv(N, 256);

    // graph preprocessing
    hipMemsetAsync(cnt, 0, (size_t)N * 4, stream);
    hist_kernel<<<cdiv(E, 256), 256, 0, stream>>>(edst_in, cnt, E);
    scan1_kernel<<<NBLK, 256, 0, stream>>>(cnt, bsum, N);
    scan2_kernel<<<1, 256, 0, stream>>>(bsum, NBLK);
    scan3_kernel<<<NBLK, 256, 0, stream>>>(cnt, bsum, rowptr, cursor, disb, selfn, N);
    fill_kernel<<<cdiv(E, 256), 256, 0, stream>>>(esrc_in, edst_in, disb, cursor, esrcb, ewb, E);

    // h0 = x @ W_in + b_in   (x_skip, fp32)
    gemm_kernel<128, false><<<cdiv(N, 128), 256, 0, stream>>>(x, Win, bin, (void*)h0, N);

    const float* hcur = h0;
    for (int i = 0; i < 4; ++i) {
        // t = h @ W_g[i] -> bf16-packed tb16
        gemm_kernel<128, true><<<cdiv(N, 128), 256, 0, stream>>>(hcur, Wg + (size_t)i * 128 * 128,
                                                                 nullptr, (void*)tb16, N);
        aggregate_kernel<<<cdiv(N, 4), 256, 0, stream>>>(tb16, rowptr, esrcb, ewb, selfn, agg, N);
        hipMemsetAsync(stats, 0, 256 * 4, stream);
        bn_stats_kernel<<<cdiv(N, 256), 256, 0, stream>>>(agg, stats, N);
        bn_finalize_kernel<<<1, 128, 0, stream>>>(stats, gamma + i * 128, beta + i * 128,
                                                  AB, 1.0f / (float)N);
        bn_apply_kernel<<<cdiv(N * 32, 256), 256, 0, stream>>>(agg, AB, h0, hbuf, accb, N * 32,
                                                               (i & 1), (i == 0) ? 1 : 0);
        hcur = hbuf;
    }

    // out = acc @ W_out + b_out  (fp32)
    gemm_kernel<64, false><<<cdiv(N, 128), 256, 0, stream>>>(accb, Wout, bout, (void*)out, N);
}

// Round 5
// 625.010 us; speedup vs baseline: 1.5789x; 1.3101x over previous
//
#include <hip/hip_runtime.h>

using short8  = __attribute__((ext_vector_type(8))) short;
using floatx4 = __attribute__((ext_vector_type(4))) float;

// ---------- bf16 helpers ----------
static __device__ __forceinline__ float bf2f(unsigned short u) {
    union { unsigned u; float f; } v; v.u = ((unsigned)u) << 16; return v.f;
}
static __device__ __forceinline__ unsigned short f2bf(float f) {
    union { float f; unsigned u; } v; v.f = f;
    unsigned r = v.u + 0x7FFFu + ((v.u >> 16) & 1u);   // round-to-nearest-even
    return (unsigned short)(r >> 16);
}

// ---------- fp32 -> bf16 bulk convert (float4 -> ushort4) ----------
__global__ void f2b_kernel(const float* __restrict__ in, unsigned short* __restrict__ out, int n4) {
    int i = blockIdx.x * 256 + threadIdx.x;
    if (i >= n4) return;
    float4 v = ((const float4*)in)[i];
    ushort4 u;
    u.x = f2bf(v.x); u.y = f2bf(v.y); u.z = f2bf(v.z); u.w = f2bf(v.w);
    ((ushort4*)out)[i] = u;
}

// ---------- weight transpose + bf16: dst[mat][m][k] = src[mat][k][m] ----------
__global__ void wt_kernel(const float* __restrict__ src, unsigned short* __restrict__ dst,
                          int K, int M, int total) {
    int i = blockIdx.x * 256 + threadIdx.x;
    if (i >= total) return;
    int m = i % M;
    int k = (i / M) % K;
    int mat = i / (M * K);
    dst[(size_t)mat * K * M + (size_t)m * K + k] = f2bf(src[i]);
}

// ---------- degree histogram ----------
__global__ void hist_kernel(const int* __restrict__ dst, int* __restrict__ cnt, int E) {
    int i = blockIdx.x * 256 + threadIdx.x;
    if (i < E) atomicAdd(&cnt[dst[i]], 1);
}

// ---------- 3-phase parallel exclusive scan over cnt[0..n) ----------
__global__ __launch_bounds__(256) void scan1_kernel(const int* __restrict__ cnt,
        int* __restrict__ bsum, int n) {
    __shared__ int s[256];
    int i = blockIdx.x * 256 + threadIdx.x;
    s[threadIdx.x] = (i < n) ? cnt[i] : 0;
    __syncthreads();
    for (int off = 128; off > 0; off >>= 1) {
        if (threadIdx.x < off) s[threadIdx.x] += s[threadIdx.x + off];
        __syncthreads();
    }
    if (threadIdx.x == 0) bsum[blockIdx.x] = s[0];
}

__global__ __launch_bounds__(256) void scan2_kernel(int* __restrict__ bsum, int nb) {
    __shared__ int s[256];
    int v = (threadIdx.x < nb) ? bsum[threadIdx.x] : 0;
    s[threadIdx.x] = v;
    __syncthreads();
    for (int off = 1; off < 256; off <<= 1) {
        int t = s[threadIdx.x];
        int a = (threadIdx.x >= off) ? s[threadIdx.x - off] : 0;
        __syncthreads();
        s[threadIdx.x] = t + a;
        __syncthreads();
    }
    if (threadIdx.x < nb) bsum[threadIdx.x] = s[threadIdx.x] - v;   // exclusive
}

__global__ __launch_bounds__(256) void scan3_kernel(const int* __restrict__ cnt,
        const int* __restrict__ boff, int* __restrict__ rowptr, int* __restrict__ cursor,
        float* __restrict__ dis, float* __restrict__ selfn, int n) {
    __shared__ int s[256];
    int i = blockIdx.x * 256 + threadIdx.x;
    int c = (i < n) ? cnt[i] : 0;
    s[threadIdx.x] = c;
    __syncthreads();
    for (int off = 1; off < 256; off <<= 1) {
        int t = s[threadIdx.x];
        int a = (threadIdx.x >= off) ? s[threadIdx.x - off] : 0;
        __syncthreads();
        s[threadIdx.x] = t + a;
        __syncthreads();
    }
    if (i < n) {
        int pre = boff[blockIdx.x] + s[threadIdx.x] - c;  // exclusive prefix
        rowptr[i] = pre;
        cursor[i] = pre;
        float d = (float)c + 1.0f;          // deg = in-degree + self-loop
        dis[i] = rsqrtf(d);
        selfn[i] = 1.0f / d;
        if (i == n - 1) rowptr[n] = pre + c;
    }
}

// ---------- CSR fill ----------
__global__ void fill_kernel(const int* __restrict__ src, const int* __restrict__ dst,
        const float* __restrict__ dis, int* __restrict__ cursor,
        int* __restrict__ esrc, float* __restrict__ ew, int E) {
    int i = blockIdx.x * 256 + threadIdx.x;
    if (i < E) {
        int s = src[i], d = dst[i];
        int p = atomicAdd(&cursor[d], 1);
        esrc[p] = s;
        ew[p] = dis[s] * dis[d];
    }
}

// ---------- MFMA bf16 GEMM: C[n x MO] = A[n x 128] @ W[128 x MO] (+bias) ----------
// A bf16 row-major; WT bf16 = W transposed [MO][128]. Block = 64 rows, 4 waves;
// wave w computes rows [w*16, w*16+16) x all MO cols via mfma_f32_16x16x32_bf16.
// Fragment layouts (m89/m91/m120-verified): A[m=lane&15][k=quad*8+j];
// B = WT[n=lane&15][k=quad*8+j]; C/D col=lane&15, row=quad*4+reg.
// LDS rows padded +8 bf16 (16B) -> ds_read_b128 2-way conflicts only (free).
template<int MO, bool OB16>
__global__ __launch_bounds__(256) void mgemm_kernel(
        const unsigned short* __restrict__ A,
        const unsigned short* __restrict__ WT,
        const float* __restrict__ bias,
        void* __restrict__ C, int nrows) {
    constexpr int NT = MO / 16;                  // col tiles (8 or 4)
    __shared__ unsigned short Al[64 * 136];
    __shared__ unsigned short Wl[MO * 136];
    const int tid   = threadIdx.x;
    const int w     = tid >> 6;
    const int lane  = tid & 63;
    const int col_l = lane & 15;
    const int quad  = lane >> 4;
    const int row_base = blockIdx.x * 64;

    // stage A: 64 rows x 16 chunks of 16B
#pragma unroll
    for (int it = 0; it < 4; ++it) {
        int idx = it * 256 + tid;
        int r = idx >> 4, ch = idx & 15;
        int gr = row_base + r; if (gr >= nrows) gr = nrows - 1;
        *(float4*)&Al[r * 136 + ch * 8] = *(const float4*)&A[(size_t)gr * 128 + ch * 8];
    }
    // stage WT: MO rows x 16 chunks of 16B (L2-resident, reused by all blocks)
#pragma unroll
    for (int it = 0; it < MO / 16; ++it) {
        int idx = it * 256 + tid;
        int r = idx >> 4, ch = idx & 15;
        *(float4*)&Wl[r * 136 + ch * 8] = *(const float4*)&WT[(size_t)r * 128 + ch * 8];
    }
    __syncthreads();

    // A fragments for this wave's 16 rows (m = col_l)
    short8 af[4];
    const int arow = w * 16 + col_l;
#pragma unroll
    for (int ks = 0; ks < 4; ++ks)
        af[ks] = *(const short8*)&Al[arow * 136 + ks * 32 + quad * 8];

    floatx4 acc[NT];
#pragma unroll
    for (int ct = 0; ct < NT; ++ct) {
        acc[ct] = (floatx4){0.f, 0.f, 0.f, 0.f};
#pragma unroll
        for (int ks = 0; ks < 4; ++ks) {
            short8 bf = *(const short8*)&Wl[(ct * 16 + col_l) * 136 + ks * 32 + quad * 8];
            acc[ct] = __builtin_amdgcn_mfma_f32_16x16x32_bf16(af[ks], bf, acc[ct], 0, 0, 0);
        }
    }

#pragma unroll
    for (int ct = 0; ct < NT; ++ct) {
        int col = ct * 16 + col_l;
        float bv = bias ? bias[col] : 0.f;
#pragma unroll
        for (int r = 0; r < 4; ++r) {
            int gr = row_base + w * 16 + quad * 4 + r;
            if (gr < nrows) {
                float o = acc[ct][r] + bv;
                if (OB16) ((unsigned short*)C)[(size_t)gr * MO + col] = f2bf(o);
                else      ((float*)C)[(size_t)gr * MO + col] = o;
            }
        }
    }
}

// ---------- CSR gather aggregation (bf16 T): one wave per node, 2 ch/lane ----------
__global__ __launch_bounds__(256) void aggregate_kernel(const unsigned short* __restrict__ T,
        const int* __restrict__ rowptr, const int* __restrict__ esrc,
        const float* __restrict__ ew, const float* __restrict__ selfn,
        float* __restrict__ AGG, int n) {
    int wave = threadIdx.x >> 6;
    int lane = threadIdx.x & 63;
    int v = blockIdx.x * 4 + wave;
    if (v >= n) return;
    int c = lane * 2;
    ushort2 tv = *(const ushort2*)&T[(size_t)v * 128 + c];
    float sn = selfn[v];
    float ax = bf2f(tv.x) * sn, ay = bf2f(tv.y) * sn;
    int e = rowptr[v], e1 = rowptr[v + 1];
    for (; e + 2 <= e1; e += 2) {
        int u0 = esrc[e], u1 = esrc[e + 1];
        float w0 = ew[e], w1 = ew[e + 1];
        ushort2 t0 = *(const ushort2*)&T[(size_t)u0 * 128 + c];
        ushort2 t1 = *(const ushort2*)&T[(size_t)u1 * 128 + c];
        ax = fmaf(w0, bf2f(t0.x), ax);
        ay = fmaf(w0, bf2f(t0.y), ay);
        ax = fmaf(w1, bf2f(t1.x), ax);
        ay = fmaf(w1, bf2f(t1.y), ay);
    }
    if (e < e1) {
        int u = esrc[e];
        float w = ew[e];
        ushort2 tu = *(const ushort2*)&T[(size_t)u * 128 + c];
        ax = fmaf(w, bf2f(tu.x), ax);
        ay = fmaf(w, bf2f(tu.y), ay);
    }
    *(float2*)&AGG[(size_t)v * 128 + c] = make_float2(ax, ay);
}

// ---------- BN stats (sum, sumsq per channel) ----------
__global__ __launch_bounds__(256) void bn_stats_kernel(const float* __restrict__ AGG,
        float* __restrict__ stats, int n) {
    __shared__ float s1[128], s2[128];
    int tid = threadIdx.x;
    int c = tid & 127;
    int half = tid >> 7;
    int v0 = blockIdx.x * 256;
    int vend = min(v0 + 256, n);
    float a1 = 0.f, a2 = 0.f;
    for (int v = v0 + half; v < vend; v += 2) {
        float x = AGG[(size_t)v * 128 + c];
        a1 += x; a2 = fmaf(x, x, a2);
    }
    if (half == 0) { s1[c] = a1; s2[c] = a2; }
    __syncthreads();
    if (half == 1) { s1[c] += a1; s2[c] += a2; }
    __syncthreads();
    if (half == 0) {
        atomicAdd(&stats[c], s1[c]);
        atomicAdd(&stats[128 + c], s2[c]);
    }
}

// ---------- BN finalize: A = inv_std*gamma, B = beta - mean*A ----------
__global__ void bn_finalize_kernel(const float* __restrict__ stats,
        const float* __restrict__ gamma, const float* __restrict__ beta,
        float* __restrict__ AB, float inv_n) {
    int c = threadIdx.x;
    float m = stats[c] * inv_n;
    float var = stats[128 + c] * inv_n - m * m;
    float inv = rsqrtf(var + 1e-5f);
    float Ax = inv * gamma[c];
    AB[c] = Ax;
    AB[128 + c] = beta[c] - m * Ax;
}

// ---------- BN apply + skip(bf16) + relu; H out bf16; ACC fp32 (+bf16 on last) ----------
__global__ __launch_bounds__(256) void bn_apply_kernel(const float* __restrict__ AGG,
        const float* __restrict__ AB, const unsigned short* __restrict__ XSKIP,
        unsigned short* __restrict__ H, float* __restrict__ ACC,
        unsigned short* __restrict__ ACC16, int total4,
        int do_skip, int first, int last) {
    int i = blockIdx.x * 256 + threadIdx.x;
    if (i >= total4) return;
    int c4 = i & 31;
    float4 x  = ((const float4*)AGG)[i];
    float4 Av = ((const float4*)AB)[c4];
    float4 Bv = ((const float4*)AB)[32 + c4];
    float4 t;
    t.x = fmaf(x.x, Av.x, Bv.x);
    t.y = fmaf(x.y, Av.y, Bv.y);
    t.z = fmaf(x.z, Av.z, Bv.z);
    t.w = fmaf(x.w, Av.w, Bv.w);
    if (do_skip) {
        ushort4 sk = ((const ushort4*)XSKIP)[i];
        t.x = fmaf(0.5f, bf2f(sk.x), t.x);
        t.y = fmaf(0.5f, bf2f(sk.y), t.y);
        t.z = fmaf(0.5f, bf2f(sk.z), t.z);
        t.w = fmaf(0.5f, bf2f(sk.w), t.w);
    }
    t.x = fmaxf(t.x, 0.f); t.y = fmaxf(t.y, 0.f);
    t.z = fmaxf(t.z, 0.f); t.w = fmaxf(t.w, 0.f);
    ushort4 hu;
    hu.x = f2bf(t.x); hu.y = f2bf(t.y); hu.z = f2bf(t.z); hu.w = f2bf(t.w);
    ((ushort4*)H)[i] = hu;
    float4 a;
    if (first) {
        a = t;
    } else {
        a = ((const float4*)ACC)[i];
        a.x += t.x; a.y += t.y; a.z += t.z; a.w += t.w;
    }
    ((float4*)ACC)[i] = a;
    if (last) {
        ushort4 au;
        au.x = f2bf(a.x); au.y = f2bf(a.y); au.z = f2bf(a.z); au.w = f2bf(a.w);
        ((ushort4*)ACC16)[i] = au;
    }
}

extern "C" void kernel_launch(void* const* d_in, const int* in_sizes, int n_in,
                              void* d_out, int out_size, void* d_ws, size_t ws_size,
                              hipStream_t stream) {
    (void)n_in; (void)out_size; (void)ws_size;
    const float* x    = (const float*)d_in[0];
    const float* Win  = (const float*)d_in[1];
    const float* bin  = (const float*)d_in[2];
    const float* Wg   = (const float*)d_in[3];
    // d_in[4] = b_g: cancelled by BN mean-subtract, unused.
    const float* gamma = (const float*)d_in[5];
    const float* beta  = (const float*)d_in[6];
    const float* Wout  = (const float*)d_in[7];
    const float* bout  = (const float*)d_in[8];
    const int*   eidx  = (const int*)d_in[9];
    float* out = (float*)d_out;

    const int N = in_sizes[0] / 128;   // 50000 nodes
    const int E = in_sizes[9] / 2;     // 600000 edges
    const int* esrc_in = eidx;
    const int* edst_in = eidx + E;

    char* p = (char*)d_ws;
    auto alloc = [&](size_t bytes) { char* r = p; p += (bytes + 255) & ~(size_t)255; return r; };
    const size_t NB  = (size_t)N * 128 * sizeof(float);
    const size_t NB2 = (size_t)N * 128 * sizeof(unsigned short);
    unsigned short* xb16  = (unsigned short*)alloc(NB2);  // x in bf16
    unsigned short* h0b   = (unsigned short*)alloc(NB2);  // x_skip / layer-0 input (bf16)
    unsigned short* tb16  = (unsigned short*)alloc(NB2);  // t (bf16)
    unsigned short* hb    = (unsigned short*)alloc(NB2);  // hidden H (bf16)
    unsigned short* acc16 = (unsigned short*)alloc(NB2);  // ACC (bf16, last layer)
    float* agg  = (float*)alloc(NB);
    float* accb = (float*)alloc(NB);
    unsigned short* WinT  = (unsigned short*)alloc(128 * 128 * 2);
    unsigned short* WgT   = (unsigned short*)alloc(4 * 128 * 128 * 2);
    unsigned short* WoutT = (unsigned short*)alloc(128 * 64 * 2);
    float* disb  = (float*)alloc((size_t)N * 4);
    float* selfn = (float*)alloc((size_t)N * 4);
    float* ewb   = (float*)alloc((size_t)E * 4);
    int*   cnt    = (int*)alloc((size_t)N * 4);
    int*   rowptr = (int*)alloc((size_t)(N + 1) * 4);
    int*   cursor = (int*)alloc((size_t)N * 4);
    int*   esrcb  = (int*)alloc((size_t)E * 4);
    int*   bsum   = (int*)alloc(256 * 4);
    float* stats  = (float*)alloc(256 * 4);
    float* AB     = (float*)alloc(256 * 4);

    auto cdiv = [](int a, int b) { return (a + b - 1) / b; };
    const int NBLK = cdiv(N, 256);

    // graph preprocessing
    hipMemsetAsync(cnt, 0, (size_t)N * 4, stream);
    hist_kernel<<<cdiv(E, 256), 256, 0, stream>>>(edst_in, cnt, E);
    scan1_kernel<<<NBLK, 256, 0, stream>>>(cnt, bsum, N);
    scan2_kernel<<<1, 256, 0, stream>>>(bsum, NBLK);
    scan3_kernel<<<NBLK, 256, 0, stream>>>(cnt, bsum, rowptr, cursor, disb, selfn, N);
    fill_kernel<<<cdiv(E, 256), 256, 0, stream>>>(esrc_in, edst_in, disb, cursor, esrcb, ewb, E);

    // dtype prep: x -> bf16; weights -> transposed bf16
    f2b_kernel<<<cdiv(N * 32, 256), 256, 0, stream>>>(x, xb16, N * 32);
    wt_kernel<<<cdiv(128 * 128, 256), 256, 0, stream>>>(Win, WinT, 128, 128, 128 * 128);
    wt_kernel<<<cdiv(4 * 128 * 128, 256), 256, 0, stream>>>(Wg, WgT, 128, 128, 4 * 128 * 128);
    wt_kernel<<<cdiv(128 * 64, 256), 256, 0, stream>>>(Wout, WoutT, 128, 64, 128 * 64);

    // h0 = x @ W_in + b_in   (bf16 out: x_skip + layer-0 input)
    mgemm_kernel<128, true><<<cdiv(N, 64), 256, 0, stream>>>(xb16, WinT, bin, (void*)h0b, N);

    const unsigned short* hcur = h0b;
    for (int i = 0; i < 4; ++i) {
        mgemm_kernel<128, true><<<cdiv(N, 64), 256, 0, stream>>>(hcur, WgT + (size_t)i * 128 * 128,
                                                                 nullptr, (void*)tb16, N);
        aggregate_kernel<<<cdiv(N, 4), 256, 0, stream>>>(tb16, rowptr, esrcb, ewb, selfn, agg, N);
        hipMemsetAsync(stats, 0, 256 * 4, stream);
        bn_stats_kernel<<<cdiv(N, 256), 256, 0, stream>>>(agg, stats, N);
        bn_finalize_kernel<<<1, 128, 0, stream>>>(stats, gamma + i * 128, beta + i * 128,
                                                  AB, 1.0f / (float)N);
        bn_apply_kernel<<<cdiv(N * 32, 256), 256, 0, stream>>>(agg, AB, h0b, hb, accb, acc16,
                                                               N * 32, (i & 1), (i == 0) ? 1 : 0,
                                                               (i == 3) ? 1 : 0);
        hcur = hb;
    }

    // out = acc @ W_out + b_out  (fp32 out)
    mgemm_kernel<64, false><<<cdiv(N, 64), 256, 0, stream>>>(acc16, WoutT, bout, (void*)out, N);
}